// Round 5
// baseline (960.264 us; speedup 1.0000x reference)
//
#include <hip/hip_runtime.h>
#include <stdint.h>

typedef unsigned short u16;
typedef uint32_t u32;
typedef __attribute__((ext_vector_type(8))) short short8;
typedef __attribute__((ext_vector_type(4))) float f32x4;

__device__ __forceinline__ float bf2f(u16 v) {
  union { u32 u; float f; } c; c.u = ((u32)v) << 16; return c.f;
}
__device__ __forceinline__ u16 f2bf(float f) {
  union { float f; u32 u; } c; c.f = f;
  u32 r = c.u + 0x7fffu + ((c.u >> 16) & 1u);  // RNE
  return (u16)(r >> 16);
}
__device__ __forceinline__ void mode_store(void* p, size_t idx, float v, u32 fm) {
  if (fm) ((float*)p)[idx] = v;
  else    ((u16*)p)[idx]   = f2bf(v);
}
__device__ __forceinline__ float load_any(const void* p, size_t i, u32 fm) {
  return fm ? ((const float*)p)[i] : bf2f(((const u16*)p)[i]);
}

enum { EPI_PLANES = 0, EPI_EMB = 1, EPI_SCORES = 2, EPI_OUT = 3 };

// ---- dtype detection: low u16 of fp32 data is random mantissa bits -> wild bf16 ----
__global__ void detect_kernel(const u32* __restrict__ x, u32* __restrict__ flag) {
  __shared__ int cnt;
  if (threadIdx.x == 0) cnt = 0;
  __syncthreads();
  int wild = 0;
  #pragma unroll
  for (int c = 0; c < 4; ++c) {
    u32 u = x[threadIdx.x * 4 + c];
    float a = fabsf(bf2f((u16)(u & 0xffff)));
    if (!(a <= 1e6f) || (a != 0.f && a < 1e-20f)) wild++;  // !(a<=..) catches NaN
  }
  atomicAdd(&cnt, wild);
  __syncthreads();
  if (threadIdx.x == 0) flag[0] = (cnt > 100) ? 1u : 0u;  // 1 = fp32 inputs
}

// ======================= fused one-shot prep =======================
struct PrepArgs {
  const void* wsrc[8];
  u16* wdst[8][3];
  const void* bsrc[8];
  float* bdst[8];
  const void* cen;
  u16* cd0; u16* cd1; u16* cd2;
  float* c2;
};

__global__ __launch_bounds__(256) void megaprep(PrepArgs P, const u32* __restrict__ flag) {
  __shared__ float t[32][33];
  const u32 fm = flag[0];
  const int b = blockIdx.x;
  const int tid = threadIdx.x;
  constexpr int RR[8] = {1024, 2048, 1024, 512, 256, 512, 1024, 2048};
  constexpr int CC[8] = {2048, 1024, 512, 256, 512, 1024, 2048, 1024};
  constexpr int WB[8] = {2048, 2048, 512, 128, 128, 512, 2048, 2048};
  constexpr int BN[8] = {2048, 1024, 512, 256, 512, 1024, 2048, 1024};
  constexpr int BB[8] = {8, 4, 2, 1, 2, 4, 8, 4};

  int s = 0;
  #pragma unroll
  for (int w = 0; w < 8; ++w) {
    if (b < s + WB[w]) {
      const int lb = b - s;
      const int Cw = CC[w], Rw = RR[w];
      const int tbx = lb % (Cw / 32), tby = lb / (Cw / 32);
      const int xx = tid & 31, yq = tid >> 5;
      #pragma unroll
      for (int yy = yq; yy < 32; yy += 8) {
        size_t src = (size_t)(tby * 32 + yy) * Cw + tbx * 32 + xx;
        t[yy][xx] = load_any(P.wsrc[w], src, fm);
      }
      __syncthreads();
      #pragma unroll
      for (int yy = yq; yy < 32; yy += 8) {
        float v = t[xx][yy];
        u16 h = f2bf(v);
        float r1 = v - bf2f(h);
        u16 m = f2bf(r1);
        u16 l = f2bf(r1 - bf2f(m));
        size_t dst = (size_t)(tbx * 32 + yy) * Rw + tby * 32 + xx;
        P.wdst[w][0][dst] = h; P.wdst[w][1][dst] = m; P.wdst[w][2][dst] = l;
      }
      return;
    }
    s += WB[w];
  }
  #pragma unroll
  for (int w = 0; w < 8; ++w) {
    if (b < s + BB[w]) {
      int i = (b - s) * 256 + tid;
      if (i < BN[w]) P.bdst[w][i] = load_any(P.bsrc[w], i, fm);
      return;
    }
    s += BB[w];
  }
  if (b < s + 256) {
    int i = (b - s) * 256 + tid;
    float v[4];
    if (fm) {
      float4 q = ((const float4*)P.cen)[i];
      v[0] = q.x; v[1] = q.y; v[2] = q.z; v[3] = q.w;
    } else {
      ushort4 q = ((const ushort4*)P.cen)[i];
      v[0] = bf2f(q.x); v[1] = bf2f(q.y); v[2] = bf2f(q.z); v[3] = bf2f(q.w);
    }
    ushort4 hh, mm, ll;
    u16* hp = (u16*)&hh; u16* mp = (u16*)&mm; u16* lp = (u16*)&ll;
    #pragma unroll
    for (int q = 0; q < 4; ++q) {
      u16 h = f2bf(v[q]);
      float r1 = v[q] - bf2f(h);
      u16 m = f2bf(r1);
      hp[q] = h; mp[q] = m; lp[q] = f2bf(r1 - bf2f(m));
    }
    ((ushort4*)P.cd0)[i] = hh; ((ushort4*)P.cd1)[i] = mm; ((ushort4*)P.cd2)[i] = ll;
    return;
  }
  s += 256;
  {
    int w = (b - s) * 4 + (tid >> 6);
    int lane = tid & 63;
    float4 v;
    if (fm) v = *(const float4*)((const float*)P.cen + (size_t)w * 256 + lane * 4);
    else {
      ushort4 q = *(const ushort4*)((const u16*)P.cen + (size_t)w * 256 + lane * 4);
      v = make_float4(bf2f(q.x), bf2f(q.y), bf2f(q.z), bf2f(q.w));
    }
    float sq = v.x * v.x + v.y * v.y + v.z * v.z + v.w * v.w;
    #pragma unroll
    for (int off = 32; off; off >>= 1) sq += __shfl_down(sq, off);
    if (lane == 0) P.c2[w] = sq;
  }
}

// ---- x chunk -> 3 bf16 planes, vec4 ----
__global__ void decomp_x4(const void* __restrict__ in, u16* __restrict__ hi,
                          u16* __restrict__ mid, u16* __restrict__ lo,
                          int n4, size_t eoff4, const u32* __restrict__ flag) {
  int i = blockIdx.x * 256 + threadIdx.x;
  if (i >= n4) return;
  u32 fm = flag[0];
  float v[4];
  if (fm) {
    float4 q = ((const float4*)in)[eoff4 + i];
    v[0] = q.x; v[1] = q.y; v[2] = q.z; v[3] = q.w;
  } else {
    ushort4 q = ((const ushort4*)in)[eoff4 + i];
    v[0] = bf2f(q.x); v[1] = bf2f(q.y); v[2] = bf2f(q.z); v[3] = bf2f(q.w);
  }
  ushort4 hh, mm, ll;
  u16* hp = (u16*)&hh; u16* mp = (u16*)&mm; u16* lp = (u16*)&ll;
  #pragma unroll
  for (int q = 0; q < 4; ++q) {
    u16 h = f2bf(v[q]);
    float r1 = v[q] - bf2f(h);
    u16 m = f2bf(r1);
    hp[q] = h; mp[q] = m; lp[q] = f2bf(r1 - bf2f(m));
  }
  ((ushort4*)hi)[i] = hh; ((ushort4*)mid)[i] = mm; ((ushort4*)lo)[i] = ll;
}

// ================= OLD proven 1-phase 128x128 kernel (small layers) =================

__device__ __forceinline__ void stage_tile128(const u16* __restrict__ g, u16* lbase,
                                              int Kst, int tid) {
  const int lane = tid & 63;
  const int wv   = tid >> 6;
  #pragma unroll
  for (int c = 0; c < 2; ++c) {
    const int li   = wv * 128 + c * 64 + lane;
    const int row  = li >> 2;
    const int colb = (li & 3) * 16;
    const char* src = (const char*)g + (size_t)row * ((size_t)Kst * 2) + colb;
    u16* dst = lbase + (size_t)(wv * 128 + c * 64) * 8;
    __builtin_amdgcn_global_load_lds(
        (const __attribute__((address_space(1))) void*)src,
        (__attribute__((address_space(3))) void*)dst, 16, 0, 0);
  }
}

template<int nA, int nW, int PCAP, int RELU, int EPI, int NOUT>
__device__ __forceinline__ void gemm_body(
    const u16* __restrict__ A0, const u16* __restrict__ A1, const u16* __restrict__ A2,
    const u16* __restrict__ W0, const u16* __restrict__ W1, const u16* __restrict__ W2,
    const float* __restrict__ bias, const float* __restrict__ c2p,
    u16* __restrict__ O0, u16* __restrict__ O1, u16* __restrict__ O2,
    float* __restrict__ outf, void* __restrict__ dout, size_t doff,
    u32 fm, int M, int N, int K, u16* lds)
{
  const int tid  = threadIdx.x;
  const int lane = tid & 63;
  const int wid  = tid >> 6;

  const int gx = gridDim.x, gy = gridDim.y;
  const int nwg = gx * gy;
  int bx = blockIdx.x, by = blockIdx.y;
  if ((nwg & 7) == 0) {
    int f0 = by * gx + bx;
    int sw = (f0 & 7) * (nwg >> 3) + (f0 >> 3);
    bx = sw % gx; by = sw / gx;
  }
  const int m0 = by * 128;
  const int n0 = bx * 128;
  const int wm = (wid & 1) * 64;
  const int wn = (wid >> 1) * 64;
  const u16* Ap[3] = {A0, A1, A2};
  const u16* Wp[3] = {W0, W1, W2};

  f32x4 acc[4][4];
  #pragma unroll
  for (int i = 0; i < 4; ++i)
    #pragma unroll
    for (int j = 0; j < 4; ++j)
      acc[i][j] = f32x4{0.f, 0.f, 0.f, 0.f};

  for (int k0 = 0; k0 < K; k0 += 32) {
    __syncthreads();
    #pragma unroll
    for (int p = 0; p < nA; ++p)
      stage_tile128(Ap[p] + (size_t)m0 * K + k0, lds + p * 4096, K, tid);
    #pragma unroll
    for (int q = 0; q < nW; ++q)
      stage_tile128(Wp[q] + (size_t)n0 * K + k0, lds + (nA + q) * 4096, K, tid);
    __syncthreads();

    short8 bfrag[nW][4];
    #pragma unroll
    for (int q = 0; q < nW; ++q)
      #pragma unroll
      for (int j = 0; j < 4; ++j) {
        int r = wn + j * 16 + (lane & 15);
        bfrag[q][j] = *(const short8*)&lds[(nA + q) * 4096 + r * 32 + (lane >> 4) * 8];
      }
    #pragma unroll
    for (int pa = 0; pa < nA; ++pa) {
      short8 afrag[4];
      #pragma unroll
      for (int i = 0; i < 4; ++i) {
        int r = wm + i * 16 + (lane & 15);
        afrag[i] = *(const short8*)&lds[pa * 4096 + r * 32 + (lane >> 4) * 8];
      }
      #pragma unroll
      for (int pw = 0; pw < nW; ++pw) {
        if (pa + pw <= PCAP) {
          #pragma unroll
          for (int i = 0; i < 4; ++i)
            #pragma unroll
            for (int j = 0; j < 4; ++j)
              acc[i][j] = __builtin_amdgcn_mfma_f32_16x16x32_bf16(
                  afrag[i], bfrag[pw][j], acc[i][j], 0, 0, 0);
        }
      }
    }
  }

  if constexpr (EPI == EPI_SCORES) {
    __shared__ float2 sarr[2][128];
    #pragma unroll
    for (int i = 0; i < 4; ++i) {
      #pragma unroll
      for (int r = 0; r < 4; ++r) {
        float mv = 3.4e38f;
        int   mi = 1 << 30;
        #pragma unroll
        for (int j = 0; j < 4; ++j) {
          int col = n0 + wn + j * 16 + (lane & 15);
          float sv = c2p[col] - 2.f * acc[i][j][r];
          if (sv < mv) { mv = sv; mi = col; }
        }
        #pragma unroll
        for (int off = 1; off < 16; off <<= 1) {
          float ov = __shfl_xor(mv, off);
          int   oi = __shfl_xor(mi, off);
          if (ov < mv || (ov == mv && oi < mi)) { mv = ov; mi = oi; }
        }
        int lrow = wm + i * 16 + (lane >> 4) * 4 + r;
        if ((lane & 15) == 0) sarr[wn >> 6][lrow] = make_float2(mv, (float)mi);
      }
    }
    __syncthreads();
    if (tid < 128) {
      float2 a = sarr[0][tid], bb = sarr[1][tid];
      float v = a.x, ix = a.y;
      if (bb.x < v || (bb.x == v && bb.y < ix)) { v = bb.x; ix = bb.y; }
      ((float2*)outf)[(size_t)(m0 + tid) * (N >> 7) + (n0 >> 7)] = make_float2(v, ix);
    }
  } else {
    #pragma unroll
    for (int i = 0; i < 4; ++i) {
      int rbase = m0 + wm + i * 16 + ((lane >> 4) * 4);
      #pragma unroll
      for (int j = 0; j < 4; ++j) {
        int col = n0 + wn + j * 16 + (lane & 15);
        float bv = bias[col];
        #pragma unroll
        for (int r = 0; r < 4; ++r) {
          float v = acc[i][j][r] + bv;
          if (RELU) v = fmaxf(v, 0.f);
          size_t idx = (size_t)(rbase + r) * N + col;
          if (NOUT >= 1) {
            u16 h = f2bf(v);
            O0[idx] = h;
            if (NOUT >= 2) {
              float r1 = v - bf2f(h);
              u16 m = f2bf(r1);
              O1[idx] = m;
              if (NOUT >= 3) O2[idx] = f2bf(r1 - bf2f(m));
            }
          }
          if (EPI == EPI_EMB || EPI == EPI_OUT) mode_store(dout, doff + idx, v, fm);
        }
      }
    }
  }
}

template<int NA, int NW, int PCAP, int RELU, int EPI, int NOUT, int ARAW>
__global__ __launch_bounds__(256)
void gemm_kernel(const u16* A0, const u16* A1, const u16* A2,
                 const u16* W0, const u16* W1, const u16* W2,
                 const float* __restrict__ bias, const float* __restrict__ c2p,
                 u16* O0, u16* O1, u16* O2,
                 float* outf, void* dout, size_t doff,
                 const u32* __restrict__ flag, int M, int N, int K)
{
  __shared__ __align__(16) u16 lds[(NA + NW) * 4096];
  const u32 fm = flag[0];
  if (fm)
    gemm_body<NA, NW, PCAP, RELU, EPI, NOUT>(A0, A1, A2, W0, W1, W2, bias, c2p,
                                             O0, O1, O2, outf, dout, doff, fm, M, N, K, lds);
  else
    gemm_body<(ARAW ? 1 : NA), 1, PCAP, RELU, EPI, NOUT>(A0, A1, A2, W0, W1, W2, bias, c2p,
                                             O0, O1, O2, outf, dout, doff, fm, M, N, K, lds);
}

// ========== NEW 2-phase double-buffered kernel (big layers; T3 minimum) ==========
// WRr=2: 8 waves, 256x128 tile. WRr=1: 4 waves, 128x128 tile. BK=32, KK compile-time.
// Per k-step: ONE __syncthreads (implicit vmcnt(0)+lgkmcnt(0) drain) -> issue next
// tile's global_load_lds into buf^1 -> ds_read + MFMA from buf. Load latency hides
// under the compute phase. LDS unit = 8KB (128 rows x 32 cols bf16); A-planes have
// WRr units (row halves), W-planes 1 unit.
template<int WRr, int nA, int nW, int PCAP, int RELU, int EPI, int NOUT, int KK>
__device__ __forceinline__ void gemm2_body(
    const u16* __restrict__ A0, const u16* __restrict__ A1, const u16* __restrict__ A2,
    const u16* __restrict__ W0, const u16* __restrict__ W1, const u16* __restrict__ W2,
    const float* __restrict__ bias,
    u16* __restrict__ O0, u16* __restrict__ O1, u16* __restrict__ O2,
    void* __restrict__ dout, size_t doff,
    u32 fm, int M, int N, u16* lds)
{
  constexpr int UNITS = nA * WRr + nW;        // 8KB LDS units per buffer
  constexpr int LOADS = UNITS * 2 / WRr;      // global_load_lds per thread per tile
  constexpr int BUFU  = UNITS * 4096;         // u16 per buffer

  const int tid  = threadIdx.x;
  const int lane = tid & 63;
  const int wid  = tid >> 6;

  const int gx = gridDim.x, gy = gridDim.y;
  const int nwg = gx * gy;
  int bx = blockIdx.x, by = blockIdx.y;
  if ((nwg & 7) == 0) {
    int f0 = by * gx + bx;
    int sw = (f0 & 7) * (nwg >> 3) + (f0 >> 3);
    bx = sw % gx; by = sw / gx;
  }
  const int m0 = by * (WRr * 128);
  const int n0 = bx * 128;
  const int wm = (wid >> 1) * 64;   // row offset within tile [0, WRr*128)
  const int wn = (wid & 1) * 64;
  const u16* Ap[3] = {A0, A1, A2};
  const u16* Wp[3] = {W0, W1, W2};

  // precompute per-load source pointers (k0 = 0); static-indexed array -> registers
  const u16* srcp[LOADS];
  #pragma unroll
  for (int c = 0; c < LOADS; ++c) {
    int blk = wid * LOADS + c;            // 64-chunk block id
    int u   = blk >> 3;                   // LDS unit
    int ci  = (blk & 7) * 64 + lane;      // chunk within unit [0,512)
    int row = ci >> 2;
    int cole = (ci & 3) * 8;              // u16 offset within row
    if (u < nA * WRr) {
      int p = u / WRr, h = u % WRr;
      srcp[c] = Ap[p] + (size_t)(m0 + h * 128 + row) * KK + cole;
    } else {
      int q = u - nA * WRr;
      srcp[c] = Wp[q] + (size_t)(n0 + row) * KK + cole;
    }
  }

  f32x4 acc[4][4];
  #pragma unroll
  for (int i = 0; i < 4; ++i)
    #pragma unroll
    for (int j = 0; j < 4; ++j)
      acc[i][j] = f32x4{0.f, 0.f, 0.f, 0.f};

  // prologue: stage tile 0 into buf 0
  #pragma unroll
  for (int c = 0; c < LOADS; ++c) {
    u16* dst = lds + (size_t)(wid * LOADS + c) * 512;
    __builtin_amdgcn_global_load_lds(
        (const __attribute__((address_space(1))) void*)(srcp[c]),
        (__attribute__((address_space(3))) void*)dst, 16, 0, 0);
  }

  int cur = 0;
  #pragma unroll 1
  for (int k0 = 0; k0 < KK; k0 += 32) {
    __syncthreads();   // drains buf[cur] loads + all waves done reading buf[cur^1]
    if (k0 + 32 < KK) {
      #pragma unroll
      for (int c = 0; c < LOADS; ++c) {
        u16* dst = lds + (cur ^ 1) * BUFU + (size_t)(wid * LOADS + c) * 512;
        __builtin_amdgcn_global_load_lds(
            (const __attribute__((address_space(1))) void*)(srcp[c] + k0 + 32),
            (__attribute__((address_space(3))) void*)dst, 16, 0, 0);
      }
    }
    __builtin_amdgcn_sched_barrier(0);  // keep stage issue ahead of compute

    const u16* bufb = lds + cur * BUFU;
    short8 bfrag[nW][4];
    #pragma unroll
    for (int q = 0; q < nW; ++q)
      #pragma unroll
      for (int j = 0; j < 4; ++j) {
        int r = wn + j * 16 + (lane & 15);
        bfrag[q][j] = *(const short8*)&bufb[(nA * WRr + q) * 4096 + r * 32 + (lane >> 4) * 8];
      }
    #pragma unroll
    for (int pa = 0; pa < nA; ++pa) {
      short8 afrag[4];
      #pragma unroll
      for (int i = 0; i < 4; ++i) {
        int r = wm + i * 16 + (lane & 15);
        afrag[i] = *(const short8*)&bufb[pa * (WRr * 4096) + r * 32 + (lane >> 4) * 8];
      }
      #pragma unroll
      for (int pw = 0; pw < nW; ++pw) {
        if (pa + pw <= PCAP) {
          #pragma unroll
          for (int i = 0; i < 4; ++i)
            #pragma unroll
            for (int j = 0; j < 4; ++j)
              acc[i][j] = __builtin_amdgcn_mfma_f32_16x16x32_bf16(
                  afrag[i], bfrag[pw][j], acc[i][j], 0, 0, 0);
        }
      }
    }
    cur ^= 1;
  }

  // epilogue: C/D layout col=lane&15, row=(lane>>4)*4+reg
  #pragma unroll
  for (int i = 0; i < 4; ++i) {
    int rbase = m0 + wm + i * 16 + ((lane >> 4) * 4);
    #pragma unroll
    for (int j = 0; j < 4; ++j) {
      int col = n0 + wn + j * 16 + (lane & 15);
      float bv = bias[col];
      #pragma unroll
      for (int r = 0; r < 4; ++r) {
        float v = acc[i][j][r] + bv;
        if (RELU) v = fmaxf(v, 0.f);
        size_t idx = (size_t)(rbase + r) * N + col;
        if (NOUT >= 1) {
          u16 h = f2bf(v);
          O0[idx] = h;
          if (NOUT >= 2) {
            float r1 = v - bf2f(h);
            u16 m = f2bf(r1);
            O1[idx] = m;
            if (NOUT >= 3) O2[idx] = f2bf(r1 - bf2f(m));
          }
        }
        if (EPI == EPI_OUT) mode_store(dout, doff + idx, v, fm);
      }
    }
  }
}

template<int WRr, int NA, int NW, int PCAP, int RELU, int EPI, int NOUT, int ARAW, int KK>
__global__ __launch_bounds__(WRr * 256, 2)
void gemm2_kernel(const u16* A0, const u16* A1, const u16* A2,
                  const u16* W0, const u16* W1, const u16* W2,
                  const float* __restrict__ bias,
                  u16* O0, u16* O1, u16* O2,
                  void* dout, size_t doff,
                  const u32* __restrict__ flag, int M, int N)
{
  __shared__ __align__(16) u16 lds[2 * (NA * WRr + NW) * 4096];
  const u32 fm = flag[0];
  if (fm)
    gemm2_body<WRr, NA, NW, PCAP, RELU, EPI, NOUT, KK>(
        A0, A1, A2, W0, W1, W2, bias, O0, O1, O2, dout, doff, fm, M, N, lds);
  else
    gemm2_body<WRr, (ARAW ? 1 : NA), 1, PCAP, RELU, EPI, NOUT, KK>(
        A0, A1, A2, W0, W1, W2, bias, O0, O1, O2, dout, doff, fm, M, N, lds);
}

// final argmin over 8 per-block partials per row -> one-hot
__global__ void argmin_final(const float2* __restrict__ pf, void* __restrict__ dout,
                             size_t doff, const u32* __restrict__ flag) {
  u32 fm  = flag[0];
  int row  = blockIdx.x * 4 + (threadIdx.x >> 6);
  int lane = threadIdx.x & 63;
  float v = 3.4e38f;
  int  mi = 1 << 30;
  if (lane < 8) {
    float2 e = pf[(size_t)row * 8 + lane];
    v = e.x; mi = (int)e.y;
  }
  #pragma unroll
  for (int off = 1; off < 8; off <<= 1) {
    float ov = __shfl_xor(v, off);
    int   oi = __shfl_xor(mi, off);
    if (ov < v || (ov == v && oi < mi)) { v = ov; mi = oi; }
  }
  int besti = __shfl(mi, 0);
  size_t eb = doff + (size_t)row * 1024 + lane * 16;
  if (fm) {
    float* op = (float*)dout;
    #pragma unroll
    for (int q = 0; q < 16; ++q)
      op[eb + q] = (lane * 16 + q == besti) ? 1.0f : 0.0f;
  } else {
    u16* op = (u16*)dout + eb;
    uint32_t w[8];
    #pragma unroll
    for (int q = 0; q < 8; ++q) {
      int c0 = lane * 16 + q * 2;
      w[q] = ((c0 == besti) ? 0x3F80u : 0u) | (((c0 + 1 == besti) ? 0x3F80u : 0u) << 16);
    }
    *(uint4*)op       = make_uint4(w[0], w[1], w[2], w[3]);
    *(uint4*)(op + 8) = make_uint4(w[4], w[5], w[6], w[7]);
  }
}

extern "C" void kernel_launch(void* const* d_in, const int* in_sizes, int n_in,
                              void* d_out, int out_size, void* d_ws, size_t ws_size,
                              hipStream_t stream) {
  const int Bn = 8192;
  const int ENC[5] = {1024, 2048, 1024, 512, 256};
  const int DEC[5] = {256, 512, 1024, 2048, 1024};

  const void* x = d_in[0];
  const void *We[4], *be[4], *Wd[4], *bd[4];
  for (int i = 0; i < 4; ++i) { We[i] = d_in[1 + 2 * i]; be[i] = d_in[2 + 2 * i]; }
  for (int i = 0; i < 4; ++i) { Wd[i] = d_in[9 + 2 * i]; bd[i] = d_in[10 + 2 * i]; }
  const void* centers = d_in[17];

  // ---- fixed workspace carve ----
  char* wsb = (char*)d_ws;
  size_t o = 0;
  auto carve = [&](size_t bytes) { void* p = wsb + o; o += (bytes + 63) & ~size_t(63); return p; };
  u32* flag = (u32*)carve(64);
  u16 *WTe[4][3], *WTd[4][3];
  for (int i = 0; i < 4; ++i)
    for (int p = 0; p < 3; ++p) WTe[i][p] = (u16*)carve((size_t)ENC[i] * ENC[i + 1] * 2);
  for (int i = 0; i < 4; ++i)
    for (int p = 0; p < 3; ++p) WTd[i][p] = (u16*)carve((size_t)DEC[i] * DEC[i + 1] * 2);
  float* bef[4]; float* bdf[4];
  for (int i = 0; i < 4; ++i) bef[i] = (float*)carve((size_t)ENC[i + 1] * 4);
  for (int i = 0; i < 4; ++i) bdf[i] = (float*)carve((size_t)DEC[i + 1] * 4);
  u16* cen[3];
  for (int p = 0; p < 3; ++p) cen[p] = (u16*)carve(1024 * 256 * 2);
  float* c2 = (float*)carve(1024 * 4);

  // ---- chunk size from remaining ws; per-chunk activation planes: 29184 B/row ----
  size_t rem = (ws_size > o) ? ws_size - o - 4096 : 0;
  int CH = 256;
  for (int c = 8192; c >= 256; c >>= 1)
    if ((size_t)c * 29184 <= rem) { CH = c; break; }
  const int nch = Bn / CH;

  u16* xp[3];  for (int p = 0; p < 3; ++p) xp[p]  = (u16*)carve((size_t)CH * 1024 * 2);
  u16* h1p[3]; for (int p = 0; p < 3; ++p) h1p[p] = (u16*)carve((size_t)CH * 2048 * 2);
  u16* h2p[3]; for (int p = 0; p < 3; ++p) h2p[p] = (u16*)carve((size_t)CH * 1024 * 2);
  u16* h3p[3]; for (int p = 0; p < 3; ++p) h3p[p] = (u16*)carve((size_t)CH * 512 * 2);
  u16* ep[3];  for (int p = 0; p < 3; ++p) ep[p]  = (u16*)carve((size_t)CH * 256 * 2);
  // overlays (stream-ordered reuse of dead regions):
  float2* pf = (float2*)xp[0];
  char* dreg = (char*)h1p[0];
  u16* g1p[2] = {(u16*)dreg,                        (u16*)(dreg + (size_t)CH * 1024)};
  u16* g2p[2] = {(u16*)(dreg + (size_t)CH * 2048),  (u16*)(dreg + (size_t)CH * 4096)};
  u16* g3p[2] = {(u16*)(dreg + (size_t)CH * 6144),  (u16*)(dreg + (size_t)CH * 10240)};

  const size_t off_emb    = (size_t)Bn * 1024;
  const size_t off_labels = (size_t)Bn * 1280;

  // ---- prep ----
  detect_kernel<<<1, 256, 0, stream>>>((const u32*)x, flag);
  {
    PrepArgs P;
    for (int i = 0; i < 4; ++i) {
      P.wsrc[i] = We[i];     P.bsrc[i] = be[i];     P.bdst[i] = bef[i];
      P.wsrc[4 + i] = Wd[i]; P.bsrc[4 + i] = bd[i]; P.bdst[4 + i] = bdf[i];
      for (int p = 0; p < 3; ++p) { P.wdst[i][p] = WTe[i][p]; P.wdst[4 + i][p] = WTd[i][p]; }
    }
    P.cen = centers; P.cd0 = cen[0]; P.cd1 = cen[1]; P.cd2 = cen[2]; P.c2 = c2;
    megaprep<<<10017, 256, 0, stream>>>(P, flag);
  }

  const int GY  = CH / 128;
  const int GY2 = CH / 256;
  for (int c = 0; c < nch; ++c) {
    decomp_x4<<<(CH * 1024 / 4 + 255) / 256, 256, 0, stream>>>(
        x, xp[0], xp[1], xp[2], CH * 1024 / 4, (size_t)c * CH * 256, flag);

    // encoder L0/L1: NEW 2-phase 8-wave 256x128
    gemm2_kernel<2, 3, 3, 2, 1, EPI_PLANES, 3, 1, 1024><<<dim3(16, GY2), 512, 0, stream>>>(
        xp[0], xp[1], xp[2], WTe[0][0], WTe[0][1], WTe[0][2], bef[0],
        h1p[0], h1p[1], h1p[2], nullptr, 0, flag, CH, 2048);
    gemm2_kernel<2, 3, 3, 2, 1, EPI_PLANES, 3, 0, 2048><<<dim3(8, GY2), 512, 0, stream>>>(
        h1p[0], h1p[1], h1p[2], WTe[1][0], WTe[1][1], WTe[1][2], bef[1],
        h2p[0], h2p[1], h2p[2], nullptr, 0, flag, CH, 1024);
    // encoder L2/L3: OLD kernel
    gemm_kernel<3, 3, 2, 1, EPI_PLANES, 3, 0><<<dim3(4, GY), 256, 0, stream>>>(
        h2p[0], h2p[1], h2p[2], WTe[2][0], WTe[2][1], WTe[2][2], bef[2], nullptr,
        h3p[0], h3p[1], h3p[2], nullptr, nullptr, 0, flag, CH, 512, 1024);
    gemm_kernel<3, 3, 2, 0, EPI_EMB, 3, 0><<<dim3(2, GY), 256, 0, stream>>>(
        h3p[0], h3p[1], h3p[2], WTe[3][0], WTe[3][1], WTe[3][2], bef[3], nullptr,
        ep[0], ep[1], ep[2], nullptr, d_out, off_emb + (size_t)c * CH * 256,
        flag, CH, 256, 512);

    // scores (fused per-block argmin) + final argmin/one-hot: OLD
    gemm_kernel<3, 3, 2, 0, EPI_SCORES, 0, 0><<<dim3(8, GY), 256, 0, stream>>>(
        ep[0], ep[1], ep[2], cen[0], cen[1], cen[2], nullptr, c2,
        nullptr, nullptr, nullptr, (float*)pf, nullptr, 0, flag, CH, 1024, 256);
    argmin_final<<<CH / 4, 256, 0, stream>>>(pf, d_out,
        off_labels + (size_t)c * CH * 1024, flag);

    // decoder D0: OLD; D1/D2/D3: NEW 2-phase 4-wave 128x128
    gemm_kernel<2, 2, 1, 1, EPI_PLANES, 2, 0><<<dim3(4, GY), 256, 0, stream>>>(
        ep[0], ep[1], nullptr, WTd[0][0], WTd[0][1], nullptr, bdf[0], nullptr,
        g1p[0], g1p[1], nullptr, nullptr, nullptr, 0, flag, CH, 512, 256);
    gemm2_kernel<1, 2, 2, 1, 1, EPI_PLANES, 2, 0, 512><<<dim3(8, GY), 256, 0, stream>>>(
        g1p[0], g1p[1], nullptr, WTd[1][0], WTd[1][1], nullptr, bdf[1],
        g2p[0], g2p[1], nullptr, nullptr, 0, flag, CH, 1024);
    gemm2_kernel<1, 2, 2, 1, 1, EPI_PLANES, 2, 0, 1024><<<dim3(16, GY), 256, 0, stream>>>(
        g2p[0], g2p[1], nullptr, WTd[2][0], WTd[2][1], nullptr, bdf[2],
        g3p[0], g3p[1], nullptr, nullptr, 0, flag, CH, 2048);
    gemm2_kernel<1, 2, 2, 1, 0, EPI_OUT, 0, 0, 2048><<<dim3(8, GY), 256, 0, stream>>>(
        g3p[0], g3p[1], nullptr, WTd[3][0], WTd[3][1], nullptr, bdf[3],
        nullptr, nullptr, nullptr, d_out, (size_t)c * CH * 1024, flag, CH, 1024);
  }

  (void)in_sizes; (void)n_in; (void)out_size;
}

// Round 6
// 917.780 us; speedup vs baseline: 1.0463x; 1.0463x over previous
//
#include <hip/hip_runtime.h>
#include <stdint.h>

typedef unsigned short u16;
typedef uint32_t u32;
typedef __attribute__((ext_vector_type(8))) short short8;
typedef __attribute__((ext_vector_type(4))) float f32x4;

__device__ __forceinline__ float bf2f(u16 v) {
  union { u32 u; float f; } c; c.u = ((u32)v) << 16; return c.f;
}
__device__ __forceinline__ u16 f2bf(float f) {
  union { float f; u32 u; } c; c.f = f;
  u32 r = c.u + 0x7fffu + ((c.u >> 16) & 1u);  // RNE
  return (u16)(r >> 16);
}
__device__ __forceinline__ void mode_store(void* p, size_t idx, float v, u32 fm) {
  if (fm) ((float*)p)[idx] = v;
  else    ((u16*)p)[idx]   = f2bf(v);
}
__device__ __forceinline__ float load_any(const void* p, size_t i, u32 fm) {
  return fm ? ((const float*)p)[i] : bf2f(((const u16*)p)[i]);
}

enum { EPI_PLANES = 0, EPI_EMB = 1, EPI_SCORES = 2, EPI_OUT = 3 };

// ---- dtype detection: low u16 of fp32 data is random mantissa bits -> wild bf16 ----
__global__ void detect_kernel(const u32* __restrict__ x, u32* __restrict__ flag) {
  __shared__ int cnt;
  if (threadIdx.x == 0) cnt = 0;
  __syncthreads();
  int wild = 0;
  #pragma unroll
  for (int c = 0; c < 4; ++c) {
    u32 u = x[threadIdx.x * 4 + c];
    float a = fabsf(bf2f((u16)(u & 0xffff)));
    if (!(a <= 1e6f) || (a != 0.f && a < 1e-20f)) wild++;  // !(a<=..) catches NaN
  }
  atomicAdd(&cnt, wild);
  __syncthreads();
  if (threadIdx.x == 0) flag[0] = (cnt > 100) ? 1u : 0u;  // 1 = fp32 inputs
}

// ======================= fused one-shot prep =======================
struct PrepArgs {
  const void* wsrc[8];
  u16* wdst[8][3];
  const void* bsrc[8];
  float* bdst[8];
  const void* cen;
  u16* cd0; u16* cd1; u16* cd2;
  float* c2;
};

__global__ __launch_bounds__(256) void megaprep(PrepArgs P, const u32* __restrict__ flag) {
  __shared__ float t[32][33];
  const u32 fm = flag[0];
  const int b = blockIdx.x;
  const int tid = threadIdx.x;
  constexpr int RR[8] = {1024, 2048, 1024, 512, 256, 512, 1024, 2048};
  constexpr int CC[8] = {2048, 1024, 512, 256, 512, 1024, 2048, 1024};
  constexpr int WB[8] = {2048, 2048, 512, 128, 128, 512, 2048, 2048};
  constexpr int BN[8] = {2048, 1024, 512, 256, 512, 1024, 2048, 1024};
  constexpr int BB[8] = {8, 4, 2, 1, 2, 4, 8, 4};

  int s = 0;
  #pragma unroll
  for (int w = 0; w < 8; ++w) {
    if (b < s + WB[w]) {
      const int lb = b - s;
      const int Cw = CC[w], Rw = RR[w];
      const int tbx = lb % (Cw / 32), tby = lb / (Cw / 32);
      const int xx = tid & 31, yq = tid >> 5;
      #pragma unroll
      for (int yy = yq; yy < 32; yy += 8) {
        size_t src = (size_t)(tby * 32 + yy) * Cw + tbx * 32 + xx;
        t[yy][xx] = load_any(P.wsrc[w], src, fm);
      }
      __syncthreads();
      #pragma unroll
      for (int yy = yq; yy < 32; yy += 8) {
        float v = t[xx][yy];
        u16 h = f2bf(v);
        float r1 = v - bf2f(h);
        u16 m = f2bf(r1);
        u16 l = f2bf(r1 - bf2f(m));
        size_t dst = (size_t)(tbx * 32 + yy) * Rw + tby * 32 + xx;
        P.wdst[w][0][dst] = h; P.wdst[w][1][dst] = m; P.wdst[w][2][dst] = l;
      }
      return;
    }
    s += WB[w];
  }
  #pragma unroll
  for (int w = 0; w < 8; ++w) {
    if (b < s + BB[w]) {
      int i = (b - s) * 256 + tid;
      if (i < BN[w]) P.bdst[w][i] = load_any(P.bsrc[w], i, fm);
      return;
    }
    s += BB[w];
  }
  if (b < s + 256) {
    int i = (b - s) * 256 + tid;
    float v[4];
    if (fm) {
      float4 q = ((const float4*)P.cen)[i];
      v[0] = q.x; v[1] = q.y; v[2] = q.z; v[3] = q.w;
    } else {
      ushort4 q = ((const ushort4*)P.cen)[i];
      v[0] = bf2f(q.x); v[1] = bf2f(q.y); v[2] = bf2f(q.z); v[3] = bf2f(q.w);
    }
    ushort4 hh, mm, ll;
    u16* hp = (u16*)&hh; u16* mp = (u16*)&mm; u16* lp = (u16*)&ll;
    #pragma unroll
    for (int q = 0; q < 4; ++q) {
      u16 h = f2bf(v[q]);
      float r1 = v[q] - bf2f(h);
      u16 m = f2bf(r1);
      hp[q] = h; mp[q] = m; lp[q] = f2bf(r1 - bf2f(m));
    }
    ((ushort4*)P.cd0)[i] = hh; ((ushort4*)P.cd1)[i] = mm; ((ushort4*)P.cd2)[i] = ll;
    return;
  }
  s += 256;
  {
    int w = (b - s) * 4 + (tid >> 6);
    int lane = tid & 63;
    float4 v;
    if (fm) v = *(const float4*)((const float*)P.cen + (size_t)w * 256 + lane * 4);
    else {
      ushort4 q = *(const ushort4*)((const u16*)P.cen + (size_t)w * 256 + lane * 4);
      v = make_float4(bf2f(q.x), bf2f(q.y), bf2f(q.z), bf2f(q.w));
    }
    float sq = v.x * v.x + v.y * v.y + v.z * v.z + v.w * v.w;
    #pragma unroll
    for (int off = 32; off; off >>= 1) sq += __shfl_down(sq, off);
    if (lane == 0) P.c2[w] = sq;
  }
}

// ---- x chunk -> 3 bf16 planes, vec4 ----
__global__ void decomp_x4(const void* __restrict__ in, u16* __restrict__ hi,
                          u16* __restrict__ mid, u16* __restrict__ lo,
                          int n4, size_t eoff4, const u32* __restrict__ flag) {
  int i = blockIdx.x * 256 + threadIdx.x;
  if (i >= n4) return;
  u32 fm = flag[0];
  float v[4];
  if (fm) {
    float4 q = ((const float4*)in)[eoff4 + i];
    v[0] = q.x; v[1] = q.y; v[2] = q.z; v[3] = q.w;
  } else {
    ushort4 q = ((const ushort4*)in)[eoff4 + i];
    v[0] = bf2f(q.x); v[1] = bf2f(q.y); v[2] = bf2f(q.z); v[3] = bf2f(q.w);
  }
  ushort4 hh, mm, ll;
  u16* hp = (u16*)&hh; u16* mp = (u16*)&mm; u16* lp = (u16*)&ll;
  #pragma unroll
  for (int q = 0; q < 4; ++q) {
    u16 h = f2bf(v[q]);
    float r1 = v[q] - bf2f(h);
    u16 m = f2bf(r1);
    hp[q] = h; mp[q] = m; lp[q] = f2bf(r1 - bf2f(m));
  }
  ((ushort4*)hi)[i] = hh; ((ushort4*)mid)[i] = mm; ((ushort4*)lo)[i] = ll;
}

// ================= proven 1-phase 128x128 kernel (multi-block overlap) =================

__device__ __forceinline__ void stage_tile128(const u16* __restrict__ g, u16* lbase,
                                              int Kst, int tid) {
  const int lane = tid & 63;
  const int wv   = tid >> 6;
  #pragma unroll
  for (int c = 0; c < 2; ++c) {
    const int li   = wv * 128 + c * 64 + lane;
    const int row  = li >> 2;
    const int colb = (li & 3) * 16;
    const char* src = (const char*)g + (size_t)row * ((size_t)Kst * 2) + colb;
    u16* dst = lbase + (size_t)(wv * 128 + c * 64) * 8;
    __builtin_amdgcn_global_load_lds(
        (const __attribute__((address_space(1))) void*)src,
        (__attribute__((address_space(3))) void*)dst, 16, 0, 0);
  }
}

template<int nA, int nW, int PCAP, int RELU, int EPI, int NOUT>
__device__ __forceinline__ void gemm_body(
    const u16* __restrict__ A0, const u16* __restrict__ A1, const u16* __restrict__ A2,
    const u16* __restrict__ W0, const u16* __restrict__ W1, const u16* __restrict__ W2,
    const float* __restrict__ bias, const float* __restrict__ c2p,
    u16* __restrict__ O0, u16* __restrict__ O1, u16* __restrict__ O2,
    float* __restrict__ outf, void* __restrict__ dout, size_t doff,
    u32 fm, int M, int N, int K, u16* lds)
{
  const int tid  = threadIdx.x;
  const int lane = tid & 63;
  const int wid  = tid >> 6;

  const int gx = gridDim.x, gy = gridDim.y;
  const int nwg = gx * gy;
  int bx = blockIdx.x, by = blockIdx.y;
  if ((nwg & 7) == 0) {
    int f0 = by * gx + bx;
    int sw = (f0 & 7) * (nwg >> 3) + (f0 >> 3);
    bx = sw % gx; by = sw / gx;
  }
  const int m0 = by * 128;
  const int n0 = bx * 128;
  const int wm = (wid & 1) * 64;
  const int wn = (wid >> 1) * 64;
  const u16* Ap[3] = {A0, A1, A2};
  const u16* Wp[3] = {W0, W1, W2};

  f32x4 acc[4][4];
  #pragma unroll
  for (int i = 0; i < 4; ++i)
    #pragma unroll
    for (int j = 0; j < 4; ++j)
      acc[i][j] = f32x4{0.f, 0.f, 0.f, 0.f};

  for (int k0 = 0; k0 < K; k0 += 32) {
    __syncthreads();
    #pragma unroll
    for (int p = 0; p < nA; ++p)
      stage_tile128(Ap[p] + (size_t)m0 * K + k0, lds + p * 4096, K, tid);
    #pragma unroll
    for (int q = 0; q < nW; ++q)
      stage_tile128(Wp[q] + (size_t)n0 * K + k0, lds + (nA + q) * 4096, K, tid);
    __syncthreads();

    short8 bfrag[nW][4];
    #pragma unroll
    for (int q = 0; q < nW; ++q)
      #pragma unroll
      for (int j = 0; j < 4; ++j) {
        int r = wn + j * 16 + (lane & 15);
        bfrag[q][j] = *(const short8*)&lds[(nA + q) * 4096 + r * 32 + (lane >> 4) * 8];
      }
    #pragma unroll
    for (int pa = 0; pa < nA; ++pa) {
      short8 afrag[4];
      #pragma unroll
      for (int i = 0; i < 4; ++i) {
        int r = wm + i * 16 + (lane & 15);
        afrag[i] = *(const short8*)&lds[pa * 4096 + r * 32 + (lane >> 4) * 8];
      }
      #pragma unroll
      for (int pw = 0; pw < nW; ++pw) {
        if (pa + pw <= PCAP) {
          #pragma unroll
          for (int i = 0; i < 4; ++i)
            #pragma unroll
            for (int j = 0; j < 4; ++j)
              acc[i][j] = __builtin_amdgcn_mfma_f32_16x16x32_bf16(
                  afrag[i], bfrag[pw][j], acc[i][j], 0, 0, 0);
        }
      }
    }
  }

  if constexpr (EPI == EPI_SCORES) {
    __shared__ float2 sarr[2][128];
    #pragma unroll
    for (int i = 0; i < 4; ++i) {
      #pragma unroll
      for (int r = 0; r < 4; ++r) {
        float mv = 3.4e38f;
        int   mi = 1 << 30;
        #pragma unroll
        for (int j = 0; j < 4; ++j) {
          int col = n0 + wn + j * 16 + (lane & 15);
          float sv = c2p[col] - 2.f * acc[i][j][r];
          if (sv < mv) { mv = sv; mi = col; }
        }
        #pragma unroll
        for (int off = 1; off < 16; off <<= 1) {
          float ov = __shfl_xor(mv, off);
          int   oi = __shfl_xor(mi, off);
          if (ov < mv || (ov == mv && oi < mi)) { mv = ov; mi = oi; }
        }
        int lrow = wm + i * 16 + (lane >> 4) * 4 + r;
        if ((lane & 15) == 0) sarr[wn >> 6][lrow] = make_float2(mv, (float)mi);
      }
    }
    __syncthreads();
    if (tid < 128) {
      float2 a = sarr[0][tid], bb = sarr[1][tid];
      float v = a.x, ix = a.y;
      if (bb.x < v || (bb.x == v && bb.y < ix)) { v = bb.x; ix = bb.y; }
      ((float2*)outf)[(size_t)(m0 + tid) * (N >> 7) + (n0 >> 7)] = make_float2(v, ix);
    }
  } else {
    #pragma unroll
    for (int i = 0; i < 4; ++i) {
      int rbase = m0 + wm + i * 16 + ((lane >> 4) * 4);
      #pragma unroll
      for (int j = 0; j < 4; ++j) {
        int col = n0 + wn + j * 16 + (lane & 15);
        float bv = bias[col];
        #pragma unroll
        for (int r = 0; r < 4; ++r) {
          float v = acc[i][j][r] + bv;
          if (RELU) v = fmaxf(v, 0.f);
          size_t idx = (size_t)(rbase + r) * N + col;
          if (NOUT >= 1) {
            u16 h = f2bf(v);
            O0[idx] = h;
            if (NOUT >= 2) {
              float r1 = v - bf2f(h);
              u16 m = f2bf(r1);
              O1[idx] = m;
              if (NOUT >= 3) O2[idx] = f2bf(r1 - bf2f(m));
            }
          }
          if (EPI == EPI_EMB || EPI == EPI_OUT) mode_store(dout, doff + idx, v, fm);
        }
      }
    }
  }
}

template<int NA, int NW, int PCAP, int RELU, int EPI, int NOUT, int ARAW>
__global__ __launch_bounds__(256)
void gemm_kernel(const u16* A0, const u16* A1, const u16* A2,
                 const u16* W0, const u16* W1, const u16* W2,
                 const float* __restrict__ bias, const float* __restrict__ c2p,
                 u16* O0, u16* O1, u16* O2,
                 float* outf, void* dout, size_t doff,
                 const u32* __restrict__ flag, int M, int N, int K)
{
  __shared__ __align__(16) u16 lds[(NA + NW) * 4096];
  const u32 fm = flag[0];
  if (fm)
    gemm_body<NA, NW, PCAP, RELU, EPI, NOUT>(A0, A1, A2, W0, W1, W2, bias, c2p,
                                             O0, O1, O2, outf, dout, doff, fm, M, N, K, lds);
  else
    gemm_body<(ARAW ? 1 : NA), 1, PCAP, RELU, EPI, NOUT>(A0, A1, A2, W0, W1, W2, bias, c2p,
                                             O0, O1, O2, outf, dout, doff, fm, M, N, K, lds);
}

// ========== 2-phase double-buffered kernel (L0/L1 only; 8-wave 256x128) ==========
template<int WRr, int nA, int nW, int PCAP, int RELU, int EPI, int NOUT, int KK>
__device__ __forceinline__ void gemm2_body(
    const u16* __restrict__ A0, const u16* __restrict__ A1, const u16* __restrict__ A2,
    const u16* __restrict__ W0, const u16* __restrict__ W1, const u16* __restrict__ W2,
    const float* __restrict__ bias,
    u16* __restrict__ O0, u16* __restrict__ O1, u16* __restrict__ O2,
    void* __restrict__ dout, size_t doff,
    u32 fm, int M, int N, u16* lds)
{
  constexpr int UNITS = nA * WRr + nW;        // 8KB LDS units per buffer
  constexpr int LOADS = UNITS * 2 / WRr;      // global_load_lds per thread per tile
  constexpr int BUFU  = UNITS * 4096;         // u16 per buffer

  const int tid  = threadIdx.x;
  const int lane = tid & 63;
  const int wid  = tid >> 6;

  const int gx = gridDim.x, gy = gridDim.y;
  const int nwg = gx * gy;
  int bx = blockIdx.x, by = blockIdx.y;
  if ((nwg & 7) == 0) {
    int f0 = by * gx + bx;
    int sw = (f0 & 7) * (nwg >> 3) + (f0 >> 3);
    bx = sw % gx; by = sw / gx;
  }
  const int m0 = by * (WRr * 128);
  const int n0 = bx * 128;
  const int wm = (wid >> 1) * 64;
  const int wn = (wid & 1) * 64;
  const u16* Ap[3] = {A0, A1, A2};
  const u16* Wp[3] = {W0, W1, W2};

  const u16* srcp[LOADS];
  #pragma unroll
  for (int c = 0; c < LOADS; ++c) {
    int blk = wid * LOADS + c;
    int u   = blk >> 3;
    int ci  = (blk & 7) * 64 + lane;
    int row = ci >> 2;
    int cole = (ci & 3) * 8;
    if (u < nA * WRr) {
      int p = u / WRr, h = u % WRr;
      srcp[c] = Ap[p] + (size_t)(m0 + h * 128 + row) * KK + cole;
    } else {
      int q = u - nA * WRr;
      srcp[c] = Wp[q] + (size_t)(n0 + row) * KK + cole;
    }
  }

  f32x4 acc[4][4];
  #pragma unroll
  for (int i = 0; i < 4; ++i)
    #pragma unroll
    for (int j = 0; j < 4; ++j)
      acc[i][j] = f32x4{0.f, 0.f, 0.f, 0.f};

  #pragma unroll
  for (int c = 0; c < LOADS; ++c) {
    u16* dst = lds + (size_t)(wid * LOADS + c) * 512;
    __builtin_amdgcn_global_load_lds(
        (const __attribute__((address_space(1))) void*)(srcp[c]),
        (__attribute__((address_space(3))) void*)dst, 16, 0, 0);
  }

  int cur = 0;
  #pragma unroll 1
  for (int k0 = 0; k0 < KK; k0 += 32) {
    __syncthreads();
    if (k0 + 32 < KK) {
      #pragma unroll
      for (int c = 0; c < LOADS; ++c) {
        u16* dst = lds + (cur ^ 1) * BUFU + (size_t)(wid * LOADS + c) * 512;
        __builtin_amdgcn_global_load_lds(
            (const __attribute__((address_space(1))) void*)(srcp[c] + k0 + 32),
            (__attribute__((address_space(3))) void*)dst, 16, 0, 0);
      }
    }
    __builtin_amdgcn_sched_barrier(0);

    const u16* bufb = lds + cur * BUFU;
    short8 bfrag[nW][4];
    #pragma unroll
    for (int q = 0; q < nW; ++q)
      #pragma unroll
      for (int j = 0; j < 4; ++j) {
        int r = wn + j * 16 + (lane & 15);
        bfrag[q][j] = *(const short8*)&bufb[(nA * WRr + q) * 4096 + r * 32 + (lane >> 4) * 8];
      }
    #pragma unroll
    for (int pa = 0; pa < nA; ++pa) {
      short8 afrag[4];
      #pragma unroll
      for (int i = 0; i < 4; ++i) {
        int r = wm + i * 16 + (lane & 15);
        afrag[i] = *(const short8*)&bufb[pa * (WRr * 4096) + r * 32 + (lane >> 4) * 8];
      }
      #pragma unroll
      for (int pw = 0; pw < nW; ++pw) {
        if (pa + pw <= PCAP) {
          #pragma unroll
          for (int i = 0; i < 4; ++i)
            #pragma unroll
            for (int j = 0; j < 4; ++j)
              acc[i][j] = __builtin_amdgcn_mfma_f32_16x16x32_bf16(
                  afrag[i], bfrag[pw][j], acc[i][j], 0, 0, 0);
        }
      }
    }
    cur ^= 1;
  }

  #pragma unroll
  for (int i = 0; i < 4; ++i) {
    int rbase = m0 + wm + i * 16 + ((lane >> 4) * 4);
    #pragma unroll
    for (int j = 0; j < 4; ++j) {
      int col = n0 + wn + j * 16 + (lane & 15);
      float bv = bias[col];
      #pragma unroll
      for (int r = 0; r < 4; ++r) {
        float v = acc[i][j][r] + bv;
        if (RELU) v = fmaxf(v, 0.f);
        size_t idx = (size_t)(rbase + r) * N + col;
        if (NOUT >= 1) {
          u16 h = f2bf(v);
          O0[idx] = h;
          if (NOUT >= 2) {
            float r1 = v - bf2f(h);
            u16 m = f2bf(r1);
            O1[idx] = m;
            if (NOUT >= 3) O2[idx] = f2bf(r1 - bf2f(m));
          }
        }
        if (EPI == EPI_OUT) mode_store(dout, doff + idx, v, fm);
      }
    }
  }
}

template<int WRr, int NA, int NW, int PCAP, int RELU, int EPI, int NOUT, int ARAW, int KK>
__global__ __launch_bounds__(WRr * 256, 2)
void gemm2_kernel(const u16* A0, const u16* A1, const u16* A2,
                  const u16* W0, const u16* W1, const u16* W2,
                  const float* __restrict__ bias,
                  u16* O0, u16* O1, u16* O2,
                  void* dout, size_t doff,
                  const u32* __restrict__ flag, int M, int N)
{
  __shared__ __align__(16) u16 lds[2 * (NA * WRr + NW) * 4096];
  const u32 fm = flag[0];
  if (fm)
    gemm2_body<WRr, NA, NW, PCAP, RELU, EPI, NOUT, KK>(
        A0, A1, A2, W0, W1, W2, bias, O0, O1, O2, dout, doff, fm, M, N, lds);
  else
    gemm2_body<WRr, (ARAW ? 1 : NA), 1, PCAP, RELU, EPI, NOUT, KK>(
        A0, A1, A2, W0, W1, W2, bias, O0, O1, O2, dout, doff, fm, M, N, lds);
}

// final argmin over 8 per-block partials per row -> one-hot
__global__ void argmin_final(const float2* __restrict__ pf, void* __restrict__ dout,
                             size_t doff, const u32* __restrict__ flag) {
  u32 fm  = flag[0];
  int row  = blockIdx.x * 4 + (threadIdx.x >> 6);
  int lane = threadIdx.x & 63;
  float v = 3.4e38f;
  int  mi = 1 << 30;
  if (lane < 8) {
    float2 e = pf[(size_t)row * 8 + lane];
    v = e.x; mi = (int)e.y;
  }
  #pragma unroll
  for (int off = 1; off < 8; off <<= 1) {
    float ov = __shfl_xor(v, off);
    int   oi = __shfl_xor(mi, off);
    if (ov < v || (ov == v && oi < mi)) { v = ov; mi = oi; }
  }
  int besti = __shfl(mi, 0);
  size_t eb = doff + (size_t)row * 1024 + lane * 16;
  if (fm) {
    float* op = (float*)dout;
    #pragma unroll
    for (int q = 0; q < 16; ++q)
      op[eb + q] = (lane * 16 + q == besti) ? 1.0f : 0.0f;
  } else {
    u16* op = (u16*)dout + eb;
    uint32_t w[8];
    #pragma unroll
    for (int q = 0; q < 8; ++q) {
      int c0 = lane * 16 + q * 2;
      w[q] = ((c0 == besti) ? 0x3F80u : 0u) | (((c0 + 1 == besti) ? 0x3F80u : 0u) << 16);
    }
    *(uint4*)op       = make_uint4(w[0], w[1], w[2], w[3]);
    *(uint4*)(op + 8) = make_uint4(w[4], w[5], w[6], w[7]);
  }
}

extern "C" void kernel_launch(void* const* d_in, const int* in_sizes, int n_in,
                              void* d_out, int out_size, void* d_ws, size_t ws_size,
                              hipStream_t stream) {
  const int Bn = 8192;
  const int ENC[5] = {1024, 2048, 1024, 512, 256};
  const int DEC[5] = {256, 512, 1024, 2048, 1024};

  const void* x = d_in[0];
  const void *We[4], *be[4], *Wd[4], *bd[4];
  for (int i = 0; i < 4; ++i) { We[i] = d_in[1 + 2 * i]; be[i] = d_in[2 + 2 * i]; }
  for (int i = 0; i < 4; ++i) { Wd[i] = d_in[9 + 2 * i]; bd[i] = d_in[10 + 2 * i]; }
  const void* centers = d_in[17];

  // ---- fixed workspace carve ----
  char* wsb = (char*)d_ws;
  size_t o = 0;
  auto carve = [&](size_t bytes) { void* p = wsb + o; o += (bytes + 63) & ~size_t(63); return p; };
  u32* flag = (u32*)carve(64);
  u16 *WTe[4][3], *WTd[4][3];
  for (int i = 0; i < 4; ++i)
    for (int p = 0; p < 3; ++p) WTe[i][p] = (u16*)carve((size_t)ENC[i] * ENC[i + 1] * 2);
  for (int i = 0; i < 4; ++i)
    for (int p = 0; p < 3; ++p) WTd[i][p] = (u16*)carve((size_t)DEC[i] * DEC[i + 1] * 2);
  float* bef[4]; float* bdf[4];
  for (int i = 0; i < 4; ++i) bef[i] = (float*)carve((size_t)ENC[i + 1] * 4);
  for (int i = 0; i < 4; ++i) bdf[i] = (float*)carve((size_t)DEC[i + 1] * 4);
  u16* cen[3];
  for (int p = 0; p < 3; ++p) cen[p] = (u16*)carve(1024 * 256 * 2);
  float* c2 = (float*)carve(1024 * 4);

  // ---- chunk size from remaining ws; per-chunk activation planes: 29184 B/row ----
  size_t rem = (ws_size > o) ? ws_size - o - 4096 : 0;
  int CH = 256;
  for (int c = 8192; c >= 256; c >>= 1)
    if ((size_t)c * 29184 <= rem) { CH = c; break; }
  const int nch = Bn / CH;

  u16* xp[3];  for (int p = 0; p < 3; ++p) xp[p]  = (u16*)carve((size_t)CH * 1024 * 2);
  u16* h1p[3]; for (int p = 0; p < 3; ++p) h1p[p] = (u16*)carve((size_t)CH * 2048 * 2);
  u16* h2p[3]; for (int p = 0; p < 3; ++p) h2p[p] = (u16*)carve((size_t)CH * 1024 * 2);
  u16* h3p[3]; for (int p = 0; p < 3; ++p) h3p[p] = (u16*)carve((size_t)CH * 512 * 2);
  u16* ep[3];  for (int p = 0; p < 3; ++p) ep[p]  = (u16*)carve((size_t)CH * 256 * 2);
  // overlays (stream-ordered reuse of dead regions):
  float2* pf = (float2*)xp[0];
  char* dreg = (char*)h1p[0];
  u16* g1p[2] = {(u16*)dreg,                        (u16*)(dreg + (size_t)CH * 1024)};
  u16* g2p[2] = {(u16*)(dreg + (size_t)CH * 2048),  (u16*)(dreg + (size_t)CH * 4096)};
  u16* g3p[2] = {(u16*)(dreg + (size_t)CH * 6144),  (u16*)(dreg + (size_t)CH * 10240)};

  const size_t off_emb    = (size_t)Bn * 1024;
  const size_t off_labels = (size_t)Bn * 1280;

  // ---- prep ----
  detect_kernel<<<1, 256, 0, stream>>>((const u32*)x, flag);
  {
    PrepArgs P;
    for (int i = 0; i < 4; ++i) {
      P.wsrc[i] = We[i];     P.bsrc[i] = be[i];     P.bdst[i] = bef[i];
      P.wsrc[4 + i] = Wd[i]; P.bsrc[4 + i] = bd[i]; P.bdst[4 + i] = bdf[i];
      for (int p = 0; p < 3; ++p) { P.wdst[i][p] = WTe[i][p]; P.wdst[4 + i][p] = WTd[i][p]; }
    }
    P.cen = centers; P.cd0 = cen[0]; P.cd1 = cen[1]; P.cd2 = cen[2]; P.c2 = c2;
    megaprep<<<10017, 256, 0, stream>>>(P, flag);
  }

  const int GY  = CH / 128;
  const int GY2 = CH / 256;
  for (int c = 0; c < nch; ++c) {
    decomp_x4<<<(CH * 1024 / 4 + 255) / 256, 256, 0, stream>>>(
        x, xp[0], xp[1], xp[2], CH * 1024 / 4, (size_t)c * CH * 256, flag);

    // encoder L0/L1: 2-phase 8-wave 256x128 (r5-verified faster here)
    gemm2_kernel<2, 3, 3, 2, 1, EPI_PLANES, 3, 1, 1024><<<dim3(16, GY2), 512, 0, stream>>>(
        xp[0], xp[1], xp[2], WTe[0][0], WTe[0][1], WTe[0][2], bef[0],
        h1p[0], h1p[1], h1p[2], nullptr, 0, flag, CH, 2048);
    gemm2_kernel<2, 3, 3, 2, 1, EPI_PLANES, 3, 0, 2048><<<dim3(8, GY2), 512, 0, stream>>>(
        h1p[0], h1p[1], h1p[2], WTe[1][0], WTe[1][1], WTe[1][2], bef[1],
        h2p[0], h2p[1], h2p[2], nullptr, 0, flag, CH, 1024);
    // encoder L2/L3: 1-phase kernel
    gemm_kernel<3, 3, 2, 1, EPI_PLANES, 3, 0><<<dim3(4, GY), 256, 0, stream>>>(
        h2p[0], h2p[1], h2p[2], WTe[2][0], WTe[2][1], WTe[2][2], bef[2], nullptr,
        h3p[0], h3p[1], h3p[2], nullptr, nullptr, 0, flag, CH, 512, 1024);
    gemm_kernel<3, 3, 2, 0, EPI_EMB, 3, 0><<<dim3(2, GY), 256, 0, stream>>>(
        h3p[0], h3p[1], h3p[2], WTe[3][0], WTe[3][1], WTe[3][2], bef[3], nullptr,
        ep[0], ep[1], ep[2], nullptr, d_out, off_emb + (size_t)c * CH * 256,
        flag, CH, 256, 512);

    // scores (fused per-block argmin) + final argmin/one-hot
    gemm_kernel<3, 3, 2, 0, EPI_SCORES, 0, 0><<<dim3(8, GY), 256, 0, stream>>>(
        ep[0], ep[1], ep[2], cen[0], cen[1], cen[2], nullptr, c2,
        nullptr, nullptr, nullptr, (float*)pf, nullptr, 0, flag, CH, 1024, 256);
    argmin_final<<<CH / 4, 256, 0, stream>>>(pf, d_out,
        off_labels + (size_t)c * CH * 1024, flag);

    // decoder: all on the 1-phase kernel (multi-block overlap; r5's gemm2 here regressed)
    gemm_kernel<2, 2, 1, 1, EPI_PLANES, 2, 0><<<dim3(4, GY), 256, 0, stream>>>(
        ep[0], ep[1], nullptr, WTd[0][0], WTd[0][1], nullptr, bdf[0], nullptr,
        g1p[0], g1p[1], nullptr, nullptr, nullptr, 0, flag, CH, 512, 256);
    gemm_kernel<2, 2, 1, 1, EPI_PLANES, 2, 0><<<dim3(8, GY), 256, 0, stream>>>(
        g1p[0], g1p[1], nullptr, WTd[1][0], WTd[1][1], nullptr, bdf[1], nullptr,
        g2p[0], g2p[1], nullptr, nullptr, nullptr, 0, flag, CH, 1024, 512);
    gemm_kernel<2, 2, 1, 1, EPI_PLANES, 2, 0><<<dim3(16, GY), 256, 0, stream>>>(
        g2p[0], g2p[1], nullptr, WTd[2][0], WTd[2][1], nullptr, bdf[2], nullptr,
        g3p[0], g3p[1], nullptr, nullptr, nullptr, 0, flag, CH, 2048, 1024);
    gemm_kernel<2, 2, 1, 0, EPI_OUT, 0, 0><<<dim3(8, GY), 256, 0, stream>>>(
        g3p[0], g3p[1], nullptr, WTd[3][0], WTd[3][1], nullptr, bdf[3], nullptr,
        nullptr, nullptr, nullptr, nullptr, d_out, (size_t)c * CH * 1024,
        flag, CH, 1024, 2048);
  }

  (void)in_sizes; (void)n_in; (void)out_size;
}

// Round 7
// 914.769 us; speedup vs baseline: 1.0497x; 1.0033x over previous
//
#include <hip/hip_runtime.h>
#include <stdint.h>

typedef unsigned short u16;
typedef uint32_t u32;
typedef __attribute__((ext_vector_type(8))) short short8;
typedef __attribute__((ext_vector_type(4))) float f32x4;

__device__ __forceinline__ float bf2f(u16 v) {
  union { u32 u; float f; } c; c.u = ((u32)v) << 16; return c.f;
}
__device__ __forceinline__ u16 f2bf(float f) {
  union { float f; u32 u; } c; c.f = f;
  u32 r = c.u + 0x7fffu + ((c.u >> 16) & 1u);  // RNE
  return (u16)(r >> 16);
}
__device__ __forceinline__ void mode_store(void* p, size_t idx, float v, u32 fm) {
  if (fm) ((float*)p)[idx] = v;
  else    ((u16*)p)[idx]   = f2bf(v);
}
__device__ __forceinline__ float load_any(const void* p, size_t i, u32 fm) {
  return fm ? ((const float*)p)[i] : bf2f(((const u16*)p)[i]);
}

// Bank-conflict swizzle (involution; touches bits 4-5, reads bits 7-8 only).
// Rows (64B) r=0..7 start at banks {0,16,8,24,4,20,12,28} -> 2 lanes/bank (free).
__device__ __forceinline__ int swz(int b) {
  return b ^ (((b >> 7) & 1) << 5) ^ (((b >> 8) & 1) << 4);
}

enum { EPI_PLANES = 0, EPI_EMB = 1, EPI_SCORES = 2, EPI_OUT = 3 };

// ---- dtype detection: low u16 of fp32 data is random mantissa bits -> wild bf16 ----
__global__ void detect_kernel(const u32* __restrict__ x, u32* __restrict__ flag) {
  __shared__ int cnt;
  if (threadIdx.x == 0) cnt = 0;
  __syncthreads();
  int wild = 0;
  #pragma unroll
  for (int c = 0; c < 4; ++c) {
    u32 u = x[threadIdx.x * 4 + c];
    float a = fabsf(bf2f((u16)(u & 0xffff)));
    if (!(a <= 1e6f) || (a != 0.f && a < 1e-20f)) wild++;  // !(a<=..) catches NaN
  }
  atomicAdd(&cnt, wild);
  __syncthreads();
  if (threadIdx.x == 0) flag[0] = (cnt > 100) ? 1u : 0u;  // 1 = fp32 inputs
}

// ======================= fused one-shot prep =======================
struct PrepArgs {
  const void* wsrc[8];
  u16* wdst[8][3];
  const void* bsrc[8];
  float* bdst[8];
  const void* cen;
  u16* cd0; u16* cd1; u16* cd2;
  float* c2;
};

__global__ __launch_bounds__(256) void megaprep(PrepArgs P, const u32* __restrict__ flag) {
  __shared__ float t[32][33];
  const u32 fm = flag[0];
  const int b = blockIdx.x;
  const int tid = threadIdx.x;
  constexpr int RR[8] = {1024, 2048, 1024, 512, 256, 512, 1024, 2048};
  constexpr int CC[8] = {2048, 1024, 512, 256, 512, 1024, 2048, 1024};
  constexpr int WB[8] = {2048, 2048, 512, 128, 128, 512, 2048, 2048};
  constexpr int BN[8] = {2048, 1024, 512, 256, 512, 1024, 2048, 1024};
  constexpr int BB[8] = {8, 4, 2, 1, 2, 4, 8, 4};

  int s = 0;
  #pragma unroll
  for (int w = 0; w < 8; ++w) {
    if (b < s + WB[w]) {
      const int lb = b - s;
      const int Cw = CC[w], Rw = RR[w];
      const int tbx = lb % (Cw / 32), tby = lb / (Cw / 32);
      const int xx = tid & 31, yq = tid >> 5;
      #pragma unroll
      for (int yy = yq; yy < 32; yy += 8) {
        size_t src = (size_t)(tby * 32 + yy) * Cw + tbx * 32 + xx;
        t[yy][xx] = load_any(P.wsrc[w], src, fm);
      }
      __syncthreads();
      #pragma unroll
      for (int yy = yq; yy < 32; yy += 8) {
        float v = t[xx][yy];
        u16 h = f2bf(v);
        float r1 = v - bf2f(h);
        u16 m = f2bf(r1);
        u16 l = f2bf(r1 - bf2f(m));
        size_t dst = (size_t)(tbx * 32 + yy) * Rw + tby * 32 + xx;
        P.wdst[w][0][dst] = h; P.wdst[w][1][dst] = m; P.wdst[w][2][dst] = l;
      }
      return;
    }
    s += WB[w];
  }
  #pragma unroll
  for (int w = 0; w < 8; ++w) {
    if (b < s + BB[w]) {
      int i = (b - s) * 256 + tid;
      if (i < BN[w]) P.bdst[w][i] = load_any(P.bsrc[w], i, fm);
      return;
    }
    s += BB[w];
  }
  if (b < s + 256) {
    int i = (b - s) * 256 + tid;
    float v[4];
    if (fm) {
      float4 q = ((const float4*)P.cen)[i];
      v[0] = q.x; v[1] = q.y; v[2] = q.z; v[3] = q.w;
    } else {
      ushort4 q = ((const ushort4*)P.cen)[i];
      v[0] = bf2f(q.x); v[1] = bf2f(q.y); v[2] = bf2f(q.z); v[3] = bf2f(q.w);
    }
    ushort4 hh, mm, ll;
    u16* hp = (u16*)&hh; u16* mp = (u16*)&mm; u16* lp = (u16*)&ll;
    #pragma unroll
    for (int q = 0; q < 4; ++q) {
      u16 h = f2bf(v[q]);
      float r1 = v[q] - bf2f(h);
      u16 m = f2bf(r1);
      hp[q] = h; mp[q] = m; lp[q] = f2bf(r1 - bf2f(m));
    }
    ((ushort4*)P.cd0)[i] = hh; ((ushort4*)P.cd1)[i] = mm; ((ushort4*)P.cd2)[i] = ll;
    return;
  }
  s += 256;
  {
    int w = (b - s) * 4 + (tid >> 6);
    int lane = tid & 63;
    float4 v;
    if (fm) v = *(const float4*)((const float*)P.cen + (size_t)w * 256 + lane * 4);
    else {
      ushort4 q = *(const ushort4*)((const u16*)P.cen + (size_t)w * 256 + lane * 4);
      v = make_float4(bf2f(q.x), bf2f(q.y), bf2f(q.z), bf2f(q.w));
    }
    float sq = v.x * v.x + v.y * v.y + v.z * v.z + v.w * v.w;
    #pragma unroll
    for (int off = 32; off; off >>= 1) sq += __shfl_down(sq, off);
    if (lane == 0) P.c2[w] = sq;
  }
}

// ---- x chunk -> 3 bf16 planes, vec4 ----
__global__ void decomp_x4(const void* __restrict__ in, u16* __restrict__ hi,
                          u16* __restrict__ mid, u16* __restrict__ lo,
                          int n4, size_t eoff4, const u32* __restrict__ flag) {
  int i = blockIdx.x * 256 + threadIdx.x;
  if (i >= n4) return;
  u32 fm = flag[0];
  float v[4];
  if (fm) {
    float4 q = ((const float4*)in)[eoff4 + i];
    v[0] = q.x; v[1] = q.y; v[2] = q.z; v[3] = q.w;
  } else {
    ushort4 q = ((const ushort4*)in)[eoff4 + i];
    v[0] = bf2f(q.x); v[1] = bf2f(q.y); v[2] = bf2f(q.z); v[3] = bf2f(q.w);
  }
  ushort4 hh, mm, ll;
  u16* hp = (u16*)&hh; u16* mp = (u16*)&mm; u16* lp = (u16*)&ll;
  #pragma unroll
  for (int q = 0; q < 4; ++q) {
    u16 h = f2bf(v[q]);
    float r1 = v[q] - bf2f(h);
    u16 m = f2bf(r1);
    hp[q] = h; mp[q] = m; lp[q] = f2bf(r1 - bf2f(m));
  }
  ((ushort4*)hi)[i] = hh; ((ushort4*)mid)[i] = mm; ((ushort4*)lo)[i] = ll;
}

// ================= proven 1-phase 128x128 kernel (multi-block overlap) =================
// Staging: linear LDS dest + INVERSE-swizzled global source; reads apply the same
// involution -> conflict-free, identical values (rule #21 both-sides).

__device__ __forceinline__ void stage_tile128(const u16* __restrict__ g, u16* lbase,
                                              int Kst, int tid) {
  const int lane = tid & 63;
  const int wv   = tid >> 6;
  #pragma unroll
  for (int c = 0; c < 2; ++c) {
    const int li   = wv * 128 + c * 64 + lane;   // 16B-chunk index, 0..511
    const int T    = swz(li * 16);               // pre-swizzled source byte in unit
    const int row  = T >> 6;
    const int colb = T & 63;
    const char* src = (const char*)g + (size_t)row * ((size_t)Kst * 2) + colb;
    u16* dst = lbase + (size_t)(wv * 128 + c * 64) * 8;  // wave-uniform, linear
    __builtin_amdgcn_global_load_lds(
        (const __attribute__((address_space(1))) void*)src,
        (__attribute__((address_space(3))) void*)dst, 16, 0, 0);
  }
}

template<int nA, int nW, int PCAP, int RELU, int EPI, int NOUT>
__device__ __forceinline__ void gemm_body(
    const u16* __restrict__ A0, const u16* __restrict__ A1, const u16* __restrict__ A2,
    const u16* __restrict__ W0, const u16* __restrict__ W1, const u16* __restrict__ W2,
    const float* __restrict__ bias, const float* __restrict__ c2p,
    u16* __restrict__ O0, u16* __restrict__ O1, u16* __restrict__ O2,
    float* __restrict__ outf, void* __restrict__ dout, size_t doff,
    u32 fm, int M, int N, int K, u16* lds)
{
  const int tid  = threadIdx.x;
  const int lane = tid & 63;
  const int wid  = tid >> 6;

  const int gx = gridDim.x, gy = gridDim.y;
  const int nwg = gx * gy;
  int bx = blockIdx.x, by = blockIdx.y;
  if ((nwg & 7) == 0) {
    int f0 = by * gx + bx;
    int sw = (f0 & 7) * (nwg >> 3) + (f0 >> 3);
    bx = sw % gx; by = sw / gx;
  }
  const int m0 = by * 128;
  const int n0 = bx * 128;
  const int wm = (wid & 1) * 64;
  const int wn = (wid >> 1) * 64;
  const u16* Ap[3] = {A0, A1, A2};
  const u16* Wp[3] = {W0, W1, W2};

  const char* ldsb = (const char*)lds;
  const int kk16 = (lane >> 4) * 16;

  f32x4 acc[4][4];
  #pragma unroll
  for (int i = 0; i < 4; ++i)
    #pragma unroll
    for (int j = 0; j < 4; ++j)
      acc[i][j] = f32x4{0.f, 0.f, 0.f, 0.f};

  for (int k0 = 0; k0 < K; k0 += 32) {
    __syncthreads();
    #pragma unroll
    for (int p = 0; p < nA; ++p)
      stage_tile128(Ap[p] + (size_t)m0 * K + k0, lds + p * 4096, K, tid);
    #pragma unroll
    for (int q = 0; q < nW; ++q)
      stage_tile128(Wp[q] + (size_t)n0 * K + k0, lds + (nA + q) * 4096, K, tid);
    __syncthreads();

    short8 bfrag[nW][4];
    #pragma unroll
    for (int q = 0; q < nW; ++q)
      #pragma unroll
      for (int j = 0; j < 4; ++j) {
        int r = wn + j * 16 + (lane & 15);
        bfrag[q][j] = *(const short8*)(ldsb + (nA + q) * 8192 + swz(r * 64 + kk16));
      }
    #pragma unroll
    for (int pa = 0; pa < nA; ++pa) {
      short8 afrag[4];
      #pragma unroll
      for (int i = 0; i < 4; ++i) {
        int r = wm + i * 16 + (lane & 15);
        afrag[i] = *(const short8*)(ldsb + pa * 8192 + swz(r * 64 + kk16));
      }
      #pragma unroll
      for (int pw = 0; pw < nW; ++pw) {
        if (pa + pw <= PCAP) {
          #pragma unroll
          for (int i = 0; i < 4; ++i)
            #pragma unroll
            for (int j = 0; j < 4; ++j)
              acc[i][j] = __builtin_amdgcn_mfma_f32_16x16x32_bf16(
                  afrag[i], bfrag[pw][j], acc[i][j], 0, 0, 0);
        }
      }
    }
  }

  if constexpr (EPI == EPI_SCORES) {
    __shared__ float2 sarr[2][128];
    #pragma unroll
    for (int i = 0; i < 4; ++i) {
      #pragma unroll
      for (int r = 0; r < 4; ++r) {
        float mv = 3.4e38f;
        int   mi = 1 << 30;
        #pragma unroll
        for (int j = 0; j < 4; ++j) {
          int col = n0 + wn + j * 16 + (lane & 15);
          float sv = c2p[col] - 2.f * acc[i][j][r];
          if (sv < mv) { mv = sv; mi = col; }
        }
        #pragma unroll
        for (int off = 1; off < 16; off <<= 1) {
          float ov = __shfl_xor(mv, off);
          int   oi = __shfl_xor(mi, off);
          if (ov < mv || (ov == mv && oi < mi)) { mv = ov; mi = oi; }
        }
        int lrow = wm + i * 16 + (lane >> 4) * 4 + r;
        if ((lane & 15) == 0) sarr[wn >> 6][lrow] = make_float2(mv, (float)mi);
      }
    }
    __syncthreads();
    if (tid < 128) {
      float2 a = sarr[0][tid], bb = sarr[1][tid];
      float v = a.x, ix = a.y;
      if (bb.x < v || (bb.x == v && bb.y < ix)) { v = bb.x; ix = bb.y; }
      ((float2*)outf)[(size_t)(m0 + tid) * (N >> 7) + (n0 >> 7)] = make_float2(v, ix);
    }
  } else {
    #pragma unroll
    for (int i = 0; i < 4; ++i) {
      int rbase = m0 + wm + i * 16 + ((lane >> 4) * 4);
      #pragma unroll
      for (int j = 0; j < 4; ++j) {
        int col = n0 + wn + j * 16 + (lane & 15);
        float bv = bias[col];
        #pragma unroll
        for (int r = 0; r < 4; ++r) {
          float v = acc[i][j][r] + bv;
          if (RELU) v = fmaxf(v, 0.f);
          size_t idx = (size_t)(rbase + r) * N + col;
          if (NOUT >= 1) {
            u16 h = f2bf(v);
            O0[idx] = h;
            if (NOUT >= 2) {
              float r1 = v - bf2f(h);
              u16 m = f2bf(r1);
              O1[idx] = m;
              if (NOUT >= 3) O2[idx] = f2bf(r1 - bf2f(m));
            }
          }
          if (EPI == EPI_EMB || EPI == EPI_OUT) mode_store(dout, doff + idx, v, fm);
        }
      }
    }
  }
}

template<int NA, int NW, int PCAP, int RELU, int EPI, int NOUT, int ARAW>
__global__ __launch_bounds__(256)
void gemm_kernel(const u16* A0, const u16* A1, const u16* A2,
                 const u16* W0, const u16* W1, const u16* W2,
                 const float* __restrict__ bias, const float* __restrict__ c2p,
                 u16* O0, u16* O1, u16* O2,
                 float* outf, void* dout, size_t doff,
                 const u32* __restrict__ flag, int M, int N, int K)
{
  __shared__ __align__(16) u16 lds[(NA + NW) * 4096];
  const u32 fm = flag[0];
  if (fm)
    gemm_body<NA, NW, PCAP, RELU, EPI, NOUT>(A0, A1, A2, W0, W1, W2, bias, c2p,
                                             O0, O1, O2, outf, dout, doff, fm, M, N, K, lds);
  else
    gemm_body<(ARAW ? 1 : NA), 1, PCAP, RELU, EPI, NOUT>(A0, A1, A2, W0, W1, W2, bias, c2p,
                                             O0, O1, O2, outf, dout, doff, fm, M, N, K, lds);
}

// ========== 2-phase double-buffered kernel (L0/L1 only; 8-wave 256x128) ==========
template<int WRr, int nA, int nW, int PCAP, int RELU, int EPI, int NOUT, int KK>
__device__ __forceinline__ void gemm2_body(
    const u16* __restrict__ A0, const u16* __restrict__ A1, const u16* __restrict__ A2,
    const u16* __restrict__ W0, const u16* __restrict__ W1, const u16* __restrict__ W2,
    const float* __restrict__ bias,
    u16* __restrict__ O0, u16* __restrict__ O1, u16* __restrict__ O2,
    void* __restrict__ dout, size_t doff,
    u32 fm, int M, int N, u16* lds)
{
  constexpr int UNITS = nA * WRr + nW;        // 8KB LDS units per buffer
  constexpr int LOADS = UNITS * 2 / WRr;      // global_load_lds per thread per tile
  constexpr int BUFU  = UNITS * 4096;         // u16 per buffer

  const int tid  = threadIdx.x;
  const int lane = tid & 63;
  const int wid  = tid >> 6;

  const int gx = gridDim.x, gy = gridDim.y;
  const int nwg = gx * gy;
  int bx = blockIdx.x, by = blockIdx.y;
  if ((nwg & 7) == 0) {
    int f0 = by * gx + bx;
    int sw = (f0 & 7) * (nwg >> 3) + (f0 >> 3);
    bx = sw % gx; by = sw / gx;
  }
  const int m0 = by * (WRr * 128);
  const int n0 = bx * 128;
  const int wm = (wid >> 1) * 64;
  const int wn = (wid & 1) * 64;
  const u16* Ap[3] = {A0, A1, A2};
  const u16* Wp[3] = {W0, W1, W2};

  // pre-swizzled per-load source pointers (k0 = 0); static-indexed -> registers
  const u16* srcp[LOADS];
  #pragma unroll
  for (int c = 0; c < LOADS; ++c) {
    int blk = wid * LOADS + c;
    int u   = blk >> 3;
    int ci  = (blk & 7) * 64 + lane;
    int T   = swz(ci * 16);               // inverse-swizzled source byte in unit
    int row = T >> 6;
    int cole = (T & 63) >> 1;             // u16 offset
    if (u < nA * WRr) {
      int p = u / WRr, h = u % WRr;
      srcp[c] = Ap[p] + (size_t)(m0 + h * 128 + row) * KK + cole;
    } else {
      int q = u - nA * WRr;
      srcp[c] = Wp[q] + (size_t)(n0 + row) * KK + cole;
    }
  }

  f32x4 acc[4][4];
  #pragma unroll
  for (int i = 0; i < 4; ++i)
    #pragma unroll
    for (int j = 0; j < 4; ++j)
      acc[i][j] = f32x4{0.f, 0.f, 0.f, 0.f};

  #pragma unroll
  for (int c = 0; c < LOADS; ++c) {
    u16* dst = lds + (size_t)(wid * LOADS + c) * 512;
    __builtin_amdgcn_global_load_lds(
        (const __attribute__((address_space(1))) void*)(srcp[c]),
        (__attribute__((address_space(3))) void*)dst, 16, 0, 0);
  }

  const int kk16 = (lane >> 4) * 16;
  int cur = 0;
  #pragma unroll 1
  for (int k0 = 0; k0 < KK; k0 += 32) {
    __syncthreads();
    if (k0 + 32 < KK) {
      #pragma unroll
      for (int c = 0; c < LOADS; ++c) {
        u16* dst = lds + (cur ^ 1) * BUFU + (size_t)(wid * LOADS + c) * 512;
        __builtin_amdgcn_global_load_lds(
            (const __attribute__((address_space(1))) void*)(srcp[c] + k0 + 32),
            (__attribute__((address_space(3))) void*)dst, 16, 0, 0);
      }
    }
    __builtin_amdgcn_sched_barrier(0);

    const char* bufb = (const char*)(lds + cur * BUFU);
    short8 bfrag[nW][4];
    #pragma unroll
    for (int q = 0; q < nW; ++q)
      #pragma unroll
      for (int j = 0; j < 4; ++j) {
        int r = wn + j * 16 + (lane & 15);
        bfrag[q][j] = *(const short8*)(bufb + (nA * WRr + q) * 8192 + swz(r * 64 + kk16));
      }
    #pragma unroll
    for (int pa = 0; pa < nA; ++pa) {
      short8 afrag[4];
      #pragma unroll
      for (int i = 0; i < 4; ++i) {
        int r = wm + i * 16 + (lane & 15);
        afrag[i] = *(const short8*)(bufb + pa * (WRr * 8192) + swz(r * 64 + kk16));
      }
      #pragma unroll
      for (int pw = 0; pw < nW; ++pw) {
        if (pa + pw <= PCAP) {
          #pragma unroll
          for (int i = 0; i < 4; ++i)
            #pragma unroll
            for (int j = 0; j < 4; ++j)
              acc[i][j] = __builtin_amdgcn_mfma_f32_16x16x32_bf16(
                  afrag[i], bfrag[pw][j], acc[i][j], 0, 0, 0);
        }
      }
    }
    cur ^= 1;
  }

  #pragma unroll
  for (int i = 0; i < 4; ++i) {
    int rbase = m0 + wm + i * 16 + ((lane >> 4) * 4);
    #pragma unroll
    for (int j = 0; j < 4; ++j) {
      int col = n0 + wn + j * 16 + (lane & 15);
      float bv = bias[col];
      #pragma unroll
      for (int r = 0; r < 4; ++r) {
        float v = acc[i][j][r] + bv;
        if (RELU) v = fmaxf(v, 0.f);
        size_t idx = (size_t)(rbase + r) * N + col;
        if (NOUT >= 1) {
          u16 h = f2bf(v);
          O0[idx] = h;
          if (NOUT >= 2) {
            float r1 = v - bf2f(h);
            u16 m = f2bf(r1);
            O1[idx] = m;
            if (NOUT >= 3) O2[idx] = f2bf(r1 - bf2f(m));
          }
        }
        if (EPI == EPI_OUT) mode_store(dout, doff + idx, v, fm);
      }
    }
  }
}

template<int WRr, int NA, int NW, int PCAP, int RELU, int EPI, int NOUT, int ARAW, int KK>
__global__ __launch_bounds__(WRr * 256, 2)
void gemm2_kernel(const u16* A0, const u16* A1, const u16* A2,
                  const u16* W0, const u16* W1, const u16* W2,
                  const float* __restrict__ bias,
                  u16* O0, u16* O1, u16* O2,
                  void* dout, size_t doff,
                  const u32* __restrict__ flag, int M, int N)
{
  __shared__ __align__(16) u16 lds[2 * (NA * WRr + NW) * 4096];
  const u32 fm = flag[0];
  if (fm)
    gemm2_body<WRr, NA, NW, PCAP, RELU, EPI, NOUT, KK>(
        A0, A1, A2, W0, W1, W2, bias, O0, O1, O2, dout, doff, fm, M, N, lds);
  else
    gemm2_body<WRr, (ARAW ? 1 : NA), 1, PCAP, RELU, EPI, NOUT, KK>(
        A0, A1, A2, W0, W1, W2, bias, O0, O1, O2, dout, doff, fm, M, N, lds);
}

// final argmin over 8 per-block partials per row -> one-hot
__global__ void argmin_final(const float2* __restrict__ pf, void* __restrict__ dout,
                             size_t doff, const u32* __restrict__ flag) {
  u32 fm  = flag[0];
  int row  = blockIdx.x * 4 + (threadIdx.x >> 6);
  int lane = threadIdx.x & 63;
  float v = 3.4e38f;
  int  mi = 1 << 30;
  if (lane < 8) {
    float2 e = pf[(size_t)row * 8 + lane];
    v = e.x; mi = (int)e.y;
  }
  #pragma unroll
  for (int off = 1; off < 8; off <<= 1) {
    float ov = __shfl_xor(v, off);
    int   oi = __shfl_xor(mi, off);
    if (ov < v || (ov == v && oi < mi)) { v = ov; mi = oi; }
  }
  int besti = __shfl(mi, 0);
  size_t eb = doff + (size_t)row * 1024 + lane * 16;
  if (fm) {
    float* op = (float*)dout;
    #pragma unroll
    for (int q = 0; q < 16; ++q)
      op[eb + q] = (lane * 16 + q == besti) ? 1.0f : 0.0f;
  } else {
    u16* op = (u16*)dout + eb;
    uint32_t w[8];
    #pragma unroll
    for (int q = 0; q < 8; ++q) {
      int c0 = lane * 16 + q * 2;
      w[q] = ((c0 == besti) ? 0x3F80u : 0u) | (((c0 + 1 == besti) ? 0x3F80u : 0u) << 16);
    }
    *(uint4*)op       = make_uint4(w[0], w[1], w[2], w[3]);
    *(uint4*)(op + 8) = make_uint4(w[4], w[5], w[6], w[7]);
  }
}

extern "C" void kernel_launch(void* const* d_in, const int* in_sizes, int n_in,
                              void* d_out, int out_size, void* d_ws, size_t ws_size,
                              hipStream_t stream) {
  const int Bn = 8192;
  const int ENC[5] = {1024, 2048, 1024, 512, 256};
  const int DEC[5] = {256, 512, 1024, 2048, 1024};

  const void* x = d_in[0];
  const void *We[4], *be[4], *Wd[4], *bd[4];
  for (int i = 0; i < 4; ++i) { We[i] = d_in[1 + 2 * i]; be[i] = d_in[2 + 2 * i]; }
  for (int i = 0; i < 4; ++i) { Wd[i] = d_in[9 + 2 * i]; bd[i] = d_in[10 + 2 * i]; }
  const void* centers = d_in[17];

  // ---- fixed workspace carve ----
  char* wsb = (char*)d_ws;
  size_t o = 0;
  auto carve = [&](size_t bytes) { void* p = wsb + o; o += (bytes + 63) & ~size_t(63); return p; };
  u32* flag = (u32*)carve(64);
  u16 *WTe[4][3], *WTd[4][3];
  for (int i = 0; i < 4; ++i)
    for (int p = 0; p < 3; ++p) WTe[i][p] = (u16*)carve((size_t)ENC[i] * ENC[i + 1] * 2);
  for (int i = 0; i < 4; ++i)
    for (int p = 0; p < 3; ++p) WTd[i][p] = (u16*)carve((size_t)DEC[i] * DEC[i + 1] * 2);
  float* bef[4]; float* bdf[4];
  for (int i = 0; i < 4; ++i) bef[i] = (float*)carve((size_t)ENC[i + 1] * 4);
  for (int i = 0; i < 4; ++i) bdf[i] = (float*)carve((size_t)DEC[i + 1] * 4);
  u16* cen[3];
  for (int p = 0; p < 3; ++p) cen[p] = (u16*)carve(1024 * 256 * 2);
  float* c2 = (float*)carve(1024 * 4);

  // ---- chunk size from remaining ws; per-chunk activation planes: 29184 B/row ----
  size_t rem = (ws_size > o) ? ws_size - o - 4096 : 0;
  int CH = 256;
  for (int c = 8192; c >= 256; c >>= 1)
    if ((size_t)c * 29184 <= rem) { CH = c; break; }
  const int nch = Bn / CH;

  u16* xp[3];  for (int p = 0; p < 3; ++p) xp[p]  = (u16*)carve((size_t)CH * 1024 * 2);
  u16* h1p[3]; for (int p = 0; p < 3; ++p) h1p[p] = (u16*)carve((size_t)CH * 2048 * 2);
  u16* h2p[3]; for (int p = 0; p < 3; ++p) h2p[p] = (u16*)carve((size_t)CH * 1024 * 2);
  u16* h3p[3]; for (int p = 0; p < 3; ++p) h3p[p] = (u16*)carve((size_t)CH * 512 * 2);
  u16* ep[3];  for (int p = 0; p < 3; ++p) ep[p]  = (u16*)carve((size_t)CH * 256 * 2);
  // overlays (stream-ordered reuse of dead regions):
  float2* pf = (float2*)xp[0];
  char* dreg = (char*)h1p[0];
  u16* g1p[2] = {(u16*)dreg,                        (u16*)(dreg + (size_t)CH * 1024)};
  u16* g2p[2] = {(u16*)(dreg + (size_t)CH * 2048),  (u16*)(dreg + (size_t)CH * 4096)};
  u16* g3p[2] = {(u16*)(dreg + (size_t)CH * 6144),  (u16*)(dreg + (size_t)CH * 10240)};

  const size_t off_emb    = (size_t)Bn * 1024;
  const size_t off_labels = (size_t)Bn * 1280;

  // ---- prep ----
  detect_kernel<<<1, 256, 0, stream>>>((const u32*)x, flag);
  {
    PrepArgs P;
    for (int i = 0; i < 4; ++i) {
      P.wsrc[i] = We[i];     P.bsrc[i] = be[i];     P.bdst[i] = bef[i];
      P.wsrc[4 + i] = Wd[i]; P.bsrc[4 + i] = bd[i]; P.bdst[4 + i] = bdf[i];
      for (int p = 0; p < 3; ++p) { P.wdst[i][p] = WTe[i][p]; P.wdst[4 + i][p] = WTd[i][p]; }
    }
    P.cen = centers; P.cd0 = cen[0]; P.cd1 = cen[1]; P.cd2 = cen[2]; P.c2 = c2;
    megaprep<<<10017, 256, 0, stream>>>(P, flag);
  }

  const int GY  = CH / 128;
  const int GY2 = CH / 256;
  for (int c = 0; c < nch; ++c) {
    decomp_x4<<<(CH * 1024 / 4 + 255) / 256, 256, 0, stream>>>(
        x, xp[0], xp[1], xp[2], CH * 1024 / 4, (size_t)c * CH * 256, flag);

    // encoder L0/L1: 2-phase 8-wave 256x128
    gemm2_kernel<2, 3, 3, 2, 1, EPI_PLANES, 3, 1, 1024><<<dim3(16, GY2), 512, 0, stream>>>(
        xp[0], xp[1], xp[2], WTe[0][0], WTe[0][1], WTe[0][2], bef[0],
        h1p[0], h1p[1], h1p[2], nullptr, 0, flag, CH, 2048);
    gemm2_kernel<2, 3, 3, 2, 1, EPI_PLANES, 3, 0, 2048><<<dim3(8, GY2), 512, 0, stream>>>(
        h1p[0], h1p[1], h1p[2], WTe[1][0], WTe[1][1], WTe[1][2], bef[1],
        h2p[0], h2p[1], h2p[2], nullptr, 0, flag, CH, 1024);
    // encoder L2/L3: 1-phase kernel
    gemm_kernel<3, 3, 2, 1, EPI_PLANES, 3, 0><<<dim3(4, GY), 256, 0, stream>>>(
        h2p[0], h2p[1], h2p[2], WTe[2][0], WTe[2][1], WTe[2][2], bef[2], nullptr,
        h3p[0], h3p[1], h3p[2], nullptr, nullptr, 0, flag, CH, 512, 1024);
    gemm_kernel<3, 3, 2, 0, EPI_EMB, 3, 0><<<dim3(2, GY), 256, 0, stream>>>(
        h3p[0], h3p[1], h3p[2], WTe[3][0], WTe[3][1], WTe[3][2], bef[3], nullptr,
        ep[0], ep[1], ep[2], nullptr, d_out, off_emb + (size_t)c * CH * 256,
        flag, CH, 256, 512);

    // scores (fused per-block argmin) + final argmin/one-hot
    gemm_kernel<3, 3, 2, 0, EPI_SCORES, 0, 0><<<dim3(8, GY), 256, 0, stream>>>(
        ep[0], ep[1], ep[2], cen[0], cen[1], cen[2], nullptr, c2,
        nullptr, nullptr, nullptr, (float*)pf, nullptr, 0, flag, CH, 1024, 256);
    argmin_final<<<CH / 4, 256, 0, stream>>>(pf, d_out,
        off_labels + (size_t)c * CH * 1024, flag);

    // decoder: 1-phase kernel (multi-block overlap)
    gemm_kernel<2, 2, 1, 1, EPI_PLANES, 2, 0><<<dim3(4, GY), 256, 0, stream>>>(
        ep[0], ep[1], nullptr, WTd[0][0], WTd[0][1], nullptr, bdf[0], nullptr,
        g1p[0], g1p[1], nullptr, nullptr, nullptr, 0, flag, CH, 512, 256);
    gemm_kernel<2, 2, 1, 1, EPI_PLANES, 2, 0><<<dim3(8, GY), 256, 0, stream>>>(
        g1p[0], g1p[1], nullptr, WTd[1][0], WTd[1][1], nullptr, bdf[1], nullptr,
        g2p[0], g2p[1], nullptr, nullptr, nullptr, 0, flag, CH, 1024, 512);
    gemm_kernel<2, 2, 1, 1, EPI_PLANES, 2, 0><<<dim3(16, GY), 256, 0, stream>>>(
        g2p[0], g2p[1], nullptr, WTd[2][0], WTd[2][1], nullptr, bdf[2], nullptr,
        g3p[0], g3p[1], nullptr, nullptr, nullptr, 0, flag, CH, 2048, 1024);
    gemm_kernel<2, 2, 1, 0, EPI_OUT, 0, 0><<<dim3(8, GY), 256, 0, stream>>>(
        g3p[0], g3p[1], nullptr, WTd[3][0], WTd[3][1], nullptr, bdf[3], nullptr,
        nullptr, nullptr, nullptr, nullptr, d_out, (size_t)c * CH * 1024,
        flag, CH, 1024, 2048);
  }

  (void)in_sizes; (void)n_in; (void)out_size;
}